// Round 4
// baseline (596.178 us; speedup 1.0000x reference)
//
#include <hip/hip_runtime.h>

// GwcVolume: group-wise correlation cost volume. FP32 in / FP32 out.
// B=1, F=320, G=40 groups, C=8 ch/group, H=128, W=256, D=48 disparities.
// lr[g,d,h,w] = (w>=d) ? mean_c L[g,c,h,w]*R[g,c,h,w-d] : 0
// rl[g,d,h,w] = lr row rotated left by d (masked head lands on rl's zero tail).
//
// Round-4: occupancy/tail fix. Evidence trail:
//  r1/r2 (write-stream restructures): 604/664us -> stream shape is NOT the
//     lever; d-major baseline structure is right.
//  r3 (rl rotated in regs, dwordx4 stores): 552us (-21). Helped via store
//     ISSUE reduction; sector-amplification theory overstated (L2 merges).
//  Remaining: kernel ~233us vs 93us traffic floor. Resource audit: LDS was
//  32KB (Rlds) + 256B (bins_s) = 33KB -> 4 blocks/CU, grid 1280 = 4x256
//  + 256-block TAIL at 1 block/CU (~20% of traffic at ~5x less MLP). In a
//  backpressure-limited kernel queue depth == throughput.
//  Fix: bins are wave-uniform (and arange) -> kill bins_s + the barrier
//  (Rlds is wave-private; same-wave ds_write->ds_read ordered by lgkmcnt).
//  LDS = exactly 32KB, __launch_bounds__(256,5) -> 5 blocks/CU, 1280 = 5x256
//  exactly: no tail, +25% resident waves.

#define G_   40
#define CPG  8
#define H_   128
#define W_   256
#define HW_  (H_ * W_)

__global__ __launch_bounds__(256, 5)
void gwc_volume_kernel(const float* __restrict__ Lp,
                       const float* __restrict__ Rp,
                       const int* __restrict__ bins,
                       float* __restrict__ out,
                       int D)
{
    __shared__ float Rlds[4 * CPG * W_];   // exactly 32 KB: per-wave right row

    const int tid = threadIdx.x;
    const int wv  = tid >> 6;        // wave 0..3
    const int ln  = tid & 63;        // lane 0..63
    const int w4  = ln << 2;         // this lane's 4 w positions: w4..w4+3

    const int row = blockIdx.x * 4 + wv;   // 0..5119
    const int g   = row >> 7;              // / H_
    const int h   = row & (H_ - 1);

    const size_t in_row = (size_t)(g * CPG) * HW_ + (size_t)h * W_;

    // Left row -> registers (pre-scaled by 1/C); right row -> LDS (private).
    float4 lf[CPG];
    float* Rw = &Rlds[wv * CPG * W_];
    #pragma unroll
    for (int c = 0; c < CPG; ++c) {
        float4 lv = *(const float4*)(Lp + in_row + (size_t)c * HW_ + w4);
        float4 rv = *(const float4*)(Rp + in_row + (size_t)c * HW_ + w4);
        lf[c] = make_float4(lv.x * 0.125f, lv.y * 0.125f,
                            lv.z * 0.125f, lv.w * 0.125f);
        *(float4*)(&Rw[c * W_ + w4]) = rv;
    }
    // No __syncthreads(): LDS region is wave-private; compiler's lgkmcnt
    // ordering covers same-wave ds_write -> ds_read.

    float* out_lr = out;
    float* out_rl = out + (size_t)G_ * D * HW_;
    const size_t obase = (size_t)g * D * HW_ + (size_t)h * W_;

    #pragma unroll 1
    for (int di0 = 0; di0 < D; di0 += 4) {
        // bins is wave-uniform; keep it scalar (no LDS staging needed).
        const int d0   = __builtin_amdgcn_readfirstlane(bins[di0]);
        const int base = w4 - d0;
        const int ihi  = (base     < 0) ? 0 : base;
        const int ilo  = (base - 4 < 0) ? 0 : base - 4;

        float4 a0 = make_float4(0.f, 0.f, 0.f, 0.f);
        float4 a1 = a0, a2 = a0, a3 = a0;

        #pragma unroll
        for (int c = 0; c < CPG; ++c) {
            const float* rr  = &Rw[c * W_];
            float4 rlo = *(const float4*)(rr + ilo);
            float4 rhi = *(const float4*)(rr + ihi);
            float4 lc  = lf[c];
            // d = d0+0 : R indices w4+j-d0 -> rhi.xyzw
            a0.x = fmaf(lc.x, rhi.x, a0.x); a0.y = fmaf(lc.y, rhi.y, a0.y);
            a0.z = fmaf(lc.z, rhi.z, a0.z); a0.w = fmaf(lc.w, rhi.w, a0.w);
            // d = d0+1
            a1.x = fmaf(lc.x, rlo.w, a1.x); a1.y = fmaf(lc.y, rhi.x, a1.y);
            a1.z = fmaf(lc.z, rhi.y, a1.z); a1.w = fmaf(lc.w, rhi.z, a1.w);
            // d = d0+2
            a2.x = fmaf(lc.x, rlo.z, a2.x); a2.y = fmaf(lc.y, rlo.w, a2.y);
            a2.z = fmaf(lc.z, rhi.x, a2.z); a2.w = fmaf(lc.w, rhi.y, a2.w);
            // d = d0+3
            a3.x = fmaf(lc.x, rlo.y, a3.x); a3.y = fmaf(lc.y, rlo.z, a3.y);
            a3.z = fmaf(lc.z, rlo.w, a3.z); a3.w = fmaf(lc.w, rhi.x, a3.w);
        }

        // Rotation lane sources (wave-uniform shift k = d0/4).
        const int k  = d0 >> 2;
        const int s0 = (ln + k)     & 63;
        const int s1 = (ln + k + 1) & 63;

        float4 av[4] = {a0, a1, a2, a3};
        #pragma unroll
        for (int dd = 0; dd < 4; ++dd) {
            float4 a   = av[dd];
            const int di = di0 + dd;
            const int d  = d0 + dd;
            float4 v;
            v.x = (w4 + 0 >= d) ? a.x : 0.f;
            v.y = (w4 + 1 >= d) ? a.y : 0.f;
            v.z = (w4 + 2 >= d) ? a.z : 0.f;
            v.w = (w4 + 3 >= d) ? a.w : 0.f;

            const size_t o = obase + (size_t)di * HW_;
            *(float4*)(out_lr + o + w4) = v;             // lr: aligned 16B

            // rl[w'] = v[(w'+d) mod 256]: in-register rotation. d = 4k+dd:
            // output comp j sources comp (j+dd)&3 of lane s0 (j+dd<4) else
            // s1 — static naming per dd. Wrapped lanes deliver the masked
            // lr head onto rl's zero tail.
            float4 r;
            if (dd == 0) {
                r.x = __shfl(v.x, s0); r.y = __shfl(v.y, s0);
                r.z = __shfl(v.z, s0); r.w = __shfl(v.w, s0);
            } else if (dd == 1) {
                r.x = __shfl(v.y, s0); r.y = __shfl(v.z, s0);
                r.z = __shfl(v.w, s0); r.w = __shfl(v.x, s1);
            } else if (dd == 2) {
                r.x = __shfl(v.z, s0); r.y = __shfl(v.w, s0);
                r.z = __shfl(v.x, s1); r.w = __shfl(v.y, s1);
            } else {
                r.x = __shfl(v.w, s0); r.y = __shfl(v.x, s1);
                r.z = __shfl(v.y, s1); r.w = __shfl(v.z, s1);
            }
            *(float4*)(out_rl + o + w4) = r;             // rl: aligned 16B
        }
    }
}

extern "C" void kernel_launch(void* const* d_in, const int* in_sizes, int n_in,
                              void* d_out, int out_size, void* d_ws, size_t ws_size,
                              hipStream_t stream) {
    const float* L  = (const float*)d_in[0];
    const float* R  = (const float*)d_in[1];
    const int* bins = (const int*)d_in[2];
    float* out      = (float*)d_out;
    const int D = in_sizes[2];                 // 48
    const int blocks = (G_ * H_) / 4;          // 1280 = 5 blocks/CU exactly
    gwc_volume_kernel<<<blocks, 256, 0, stream>>>(L, R, bins, out, D);
}